// Round 1
// baseline (696.828 us; speedup 1.0000x reference)
//
#include <hip/hip_runtime.h>
#include <hip/hip_fp16.h>

#define MM 2048
#define NN 2048
#define DD 512
#define NA 2049        // augmented dim (m+1 = n+1)
#define LDH 2056       // fp16 padded row stride (4112 B, 16B-aligned)
#define ITERS 100

// ---------------------------------------------------------------------------
// init: c = 1, augmented row/col of K0 (f32 in d_out K-region, fp16 in ws)
// ---------------------------------------------------------------------------
__global__ __launch_bounds__(256) void init_fill(float* __restrict__ Kreg,
                                                 _Float16* __restrict__ K0h,
                                                 float* __restrict__ c,
                                                 const float* __restrict__ zp) {
    int t = blockIdx.x * 256 + threadIdx.x;
    float e5 = expf(zp[0] * 10.0f);   // exp(z/eps)
    if (t < NA) {
        c[t] = 1.0f;
        Kreg[(size_t)2048 * NA + t] = e5;            // last row (incl corner)
        K0h[(size_t)2048 * LDH + t] = (_Float16)e5;
    }
    if (t < MM) {
        Kreg[(size_t)t * NA + 2048] = e5;            // last col, rows 0..2047
        K0h[(size_t)t * LDH + 2048] = (_Float16)e5;
    }
}

// ---------------------------------------------------------------------------
// f32 GEMM (Q @ R^T) fused with exp(score*10); writes f32 K0 + fp16 K0
// 64x64 tile per WG, 256 threads, 4x4 outputs/thread, BK=16
// ---------------------------------------------------------------------------
__global__ __launch_bounds__(256) void gemm_exp(const float* __restrict__ Q,
                                                const float* __restrict__ Rm,
                                                float* __restrict__ Kreg,
                                                _Float16* __restrict__ K0h) {
    __shared__ float As[16][64];
    __shared__ float Bs[16][64];
    const int tid = threadIdx.x;
    const int row0 = blockIdx.y * 64, col0 = blockIdx.x * 64;
    const int tx = tid & 15, ty = tid >> 4;
    const int lr = tid >> 2;          // 0..63: row within tile for loading
    const int lk = (tid & 3) * 4;     // k offset 0,4,8,12

    float acc[4][4] = {};
    for (int k0 = 0; k0 < DD; k0 += 16) {
        float4 a = *(const float4*)(Q  + (size_t)(row0 + lr) * DD + k0 + lk);
        float4 b = *(const float4*)(Rm + (size_t)(col0 + lr) * DD + k0 + lk);
        __syncthreads();
        As[lk + 0][lr] = a.x; As[lk + 1][lr] = a.y;
        As[lk + 2][lr] = a.z; As[lk + 3][lr] = a.w;
        Bs[lk + 0][lr] = b.x; Bs[lk + 1][lr] = b.y;
        Bs[lk + 2][lr] = b.z; Bs[lk + 3][lr] = b.w;
        __syncthreads();
#pragma unroll
        for (int kk = 0; kk < 16; ++kk) {
            float4 av = *(const float4*)&As[kk][ty * 4];
            float4 bv = *(const float4*)&Bs[kk][tx * 4];
            float aa[4] = {av.x, av.y, av.z, av.w};
            float bb[4] = {bv.x, bv.y, bv.z, bv.w};
#pragma unroll
            for (int i = 0; i < 4; ++i)
#pragma unroll
                for (int j = 0; j < 4; ++j)
                    acc[i][j] += aa[i] * bb[j];
        }
    }
#pragma unroll
    for (int i = 0; i < 4; ++i) {
        const int rr = row0 + ty * 4 + i;
#pragma unroll
        for (int j = 0; j < 4; ++j) {
            const int cc = col0 + tx * 4 + j;
            float v = expf(acc[i][j] * 10.0f);
            Kreg[(size_t)rr * NA + cc] = v;
            K0h[(size_t)rr * LDH + cc] = (_Float16)v;
        }
    }
}

// ---------------------------------------------------------------------------
// fp16 transpose (full 2049x2049 incl augmented entries), LDS 64x64 tiles
// ---------------------------------------------------------------------------
__global__ __launch_bounds__(256) void transpose_h(const _Float16* __restrict__ src,
                                                   _Float16* __restrict__ dst) {
    __shared__ _Float16 t[64][65];
    const int x0 = blockIdx.x * 64, y0 = blockIdx.y * 64;
    const int lx = threadIdx.x & 63, lyb = threadIdx.x >> 6;
    for (int ly = lyb; ly < 64; ly += 4) {
        int y = y0 + ly, x = x0 + lx;
        if (y < NA && x < NA) t[ly][lx] = src[(size_t)y * LDH + x];
    }
    __syncthreads();
    for (int ly = lyb; ly < 64; ly += 4) {
        int y = x0 + ly, x = y0 + lx;        // transposed coordinates
        if (y < NA && x < NA) dst[(size_t)y * LDH + x] = t[lx][ly];
    }
}

// ---------------------------------------------------------------------------
// matvec + reciprocal: vout = 1 / (Kh @ vin).  One wave per row.
// ---------------------------------------------------------------------------
__global__ __launch_bounds__(256) void matvec_recip(const _Float16* __restrict__ Kh,
                                                    const float* __restrict__ vin,
                                                    float* __restrict__ vout) {
    const int wave = threadIdx.x >> 6, lane = threadIdx.x & 63;
    const int row = blockIdx.x * 4 + wave;
    if (row >= NA) return;
    const _Float16* Krow = Kh + (size_t)row * LDH;
    float sum = 0.0f;
#pragma unroll
    for (int s = 0; s < 4; ++s) {
        const int j = (s * 64 + lane) * 8;
        union { uint4 u; _Float16 h[8]; } kv;
        kv.u = *(const uint4*)(Krow + j);
        float4 c0 = *(const float4*)(vin + j);
        float4 c1 = *(const float4*)(vin + j + 4);
        sum += (float)kv.h[0] * c0.x + (float)kv.h[1] * c0.y +
               (float)kv.h[2] * c0.z + (float)kv.h[3] * c0.w +
               (float)kv.h[4] * c1.x + (float)kv.h[5] * c1.y +
               (float)kv.h[6] * c1.z + (float)kv.h[7] * c1.w;
    }
    if (lane == 0) sum += (float)Krow[2048] * vin[2048];   // remainder element
#pragma unroll
    for (int off = 32; off; off >>= 1) sum += __shfl_xor(sum, off, 64);
    if (lane == 0) vout[row] = 1.0f / sum;
}

// ---------------------------------------------------------------------------
// finalize: K = diag(r) K0 diag(c) in place (f32), P = K[:M,:N]
// ---------------------------------------------------------------------------
__global__ __launch_bounds__(256) void finalize(const float* __restrict__ r,
                                                const float* __restrict__ c,
                                                float* __restrict__ Kreg,
                                                float* __restrict__ P) {
    const int row = blockIdx.x;
    const float rs = r[row];
    for (int col = threadIdx.x; col < NA; col += 256) {
        float v = Kreg[(size_t)row * NA + col] * rs * c[col];
        Kreg[(size_t)row * NA + col] = v;
        if (row < MM && col < NN) P[(size_t)row * NN + col] = v;
    }
}

// ---------------------------------------------------------------------------
extern "C" void kernel_launch(void* const* d_in, const int* in_sizes, int n_in,
                              void* d_out, int out_size, void* d_ws, size_t ws_size,
                              hipStream_t stream) {
    const float* Q  = (const float*)d_in[0];
    const float* Rm = (const float*)d_in[1];
    const float* zp = (const float*)d_in[2];

    float* P    = (float*)d_out;
    float* Kreg = P + (size_t)MM * NN;       // f32 K0 / final K lives in d_out

    char* ws = (char*)d_ws;
    const size_t HBYTES = 8425728;           // NA*LDH*2 = 8,425,488 -> 256-aligned
    _Float16* K0h  = (_Float16*)ws;
    _Float16* K0hT = (_Float16*)(ws + HBYTES);
    float* c = (float*)(ws + 2 * HBYTES);
    float* r = c + 2560;

    init_fill<<<dim3(9), dim3(256), 0, stream>>>(Kreg, K0h, c, zp);
    gemm_exp<<<dim3(32, 32), dim3(256), 0, stream>>>(Q, Rm, Kreg, K0h);
    transpose_h<<<dim3(33, 33), dim3(256), 0, stream>>>(K0h, K0hT);
    for (int it = 0; it < ITERS; ++it) {
        matvec_recip<<<dim3(513), dim3(256), 0, stream>>>(K0h,  c, r);
        matvec_recip<<<dim3(513), dim3(256), 0, stream>>>(K0hT, r, c);
    }
    finalize<<<dim3(2049), dim3(256), 0, stream>>>(r, c, Kreg, P);
}

// Round 2
// 166.272 us; speedup vs baseline: 4.1909x; 4.1909x over previous
//
#include <hip/hip_runtime.h>
#include <hip/hip_fp16.h>

#define MM 2048
#define NN 2048
#define DD 512
#define NA 2049        // augmented dim (m+1 = n+1)
#define LDH 2056       // fp16 padded row stride (4112 B, 16B-aligned)
#define ITERS 100
#define NWG 257        // persistent grid: 257 WGs x 512 thr = 2056 waves >= 2049 rows
#define TPB 512

// ---------------------------------------------------------------------------
// init: c = 1, augmented row/col of K0, zero barrier/convergence control block
// ---------------------------------------------------------------------------
__global__ __launch_bounds__(256) void init_fill(float* __restrict__ Kreg,
                                                 _Float16* __restrict__ K0h,
                                                 float* __restrict__ c,
                                                 unsigned* __restrict__ ctrl,
                                                 const float* __restrict__ zp) {
    int t = blockIdx.x * 256 + threadIdx.x;
    float e5 = expf(zp[0] * 10.0f);   // exp(z/eps)
    if (t < 512) ctrl[t] = 0u;        // barrier slots + per-iter changed flags
    if (t < NA) {
        c[t] = 1.0f;
        Kreg[(size_t)2048 * NA + t] = e5;            // last row (incl corner)
        K0h[(size_t)2048 * LDH + t] = (_Float16)e5;
    }
    if (t < MM) {
        Kreg[(size_t)t * NA + 2048] = e5;            // last col, rows 0..2047
        K0h[(size_t)t * LDH + 2048] = (_Float16)e5;
    }
}

// ---------------------------------------------------------------------------
// f32 GEMM (Q @ R^T) fused with exp(score*10); writes f32 K0 + fp16 K0
// ---------------------------------------------------------------------------
__global__ __launch_bounds__(256) void gemm_exp(const float* __restrict__ Q,
                                                const float* __restrict__ Rm,
                                                float* __restrict__ Kreg,
                                                _Float16* __restrict__ K0h) {
    __shared__ float As[16][64];
    __shared__ float Bs[16][64];
    const int tid = threadIdx.x;
    const int row0 = blockIdx.y * 64, col0 = blockIdx.x * 64;
    const int tx = tid & 15, ty = tid >> 4;
    const int lr = tid >> 2;
    const int lk = (tid & 3) * 4;

    float acc[4][4] = {};
    for (int k0 = 0; k0 < DD; k0 += 16) {
        float4 a = *(const float4*)(Q  + (size_t)(row0 + lr) * DD + k0 + lk);
        float4 b = *(const float4*)(Rm + (size_t)(col0 + lr) * DD + k0 + lk);
        __syncthreads();
        As[lk + 0][lr] = a.x; As[lk + 1][lr] = a.y;
        As[lk + 2][lr] = a.z; As[lk + 3][lr] = a.w;
        Bs[lk + 0][lr] = b.x; Bs[lk + 1][lr] = b.y;
        Bs[lk + 2][lr] = b.z; Bs[lk + 3][lr] = b.w;
        __syncthreads();
#pragma unroll
        for (int kk = 0; kk < 16; ++kk) {
            float4 av = *(const float4*)&As[kk][ty * 4];
            float4 bv = *(const float4*)&Bs[kk][tx * 4];
            float aa[4] = {av.x, av.y, av.z, av.w};
            float bb[4] = {bv.x, bv.y, bv.z, bv.w};
#pragma unroll
            for (int i = 0; i < 4; ++i)
#pragma unroll
                for (int j = 0; j < 4; ++j)
                    acc[i][j] += aa[i] * bb[j];
        }
    }
#pragma unroll
    for (int i = 0; i < 4; ++i) {
        const int rr = row0 + ty * 4 + i;
#pragma unroll
        for (int j = 0; j < 4; ++j) {
            const int cc = col0 + tx * 4 + j;
            float v = expf(acc[i][j] * 10.0f);
            Kreg[(size_t)rr * NA + cc] = v;
            K0h[(size_t)rr * LDH + cc] = (_Float16)v;
        }
    }
}

// ---------------------------------------------------------------------------
// fp16 transpose (full 2049x2049 incl augmented entries)
// ---------------------------------------------------------------------------
__global__ __launch_bounds__(256) void transpose_h(const _Float16* __restrict__ src,
                                                   _Float16* __restrict__ dst) {
    __shared__ _Float16 t[64][65];
    const int x0 = blockIdx.x * 64, y0 = blockIdx.y * 64;
    const int lx = threadIdx.x & 63, lyb = threadIdx.x >> 6;
    for (int ly = lyb; ly < 64; ly += 4) {
        int y = y0 + ly, x = x0 + lx;
        if (y < NA && x < NA) t[ly][lx] = src[(size_t)y * LDH + x];
    }
    __syncthreads();
    for (int ly = lyb; ly < 64; ly += 4) {
        int y = x0 + ly, x = y0 + lx;
        if (y < NA && x < NA) dst[(size_t)y * LDH + x] = t[lx][ly];
    }
}

// ---------------------------------------------------------------------------
// persistent Sinkhorn loop: slotted grid barrier, one row per wave
// ---------------------------------------------------------------------------
__device__ __forceinline__ void grid_barrier(unsigned* slot) {
    __syncthreads();
    if (threadIdx.x == 0) {
        __hip_atomic_fetch_add(slot, 1u, __ATOMIC_ACQ_REL, __HIP_MEMORY_SCOPE_AGENT);
        while (__hip_atomic_load(slot, __ATOMIC_ACQUIRE, __HIP_MEMORY_SCOPE_AGENT)
               != (unsigned)NWG)
            __builtin_amdgcn_s_sleep(1);
    }
    __syncthreads();
}

__device__ __forceinline__ float rowdot(const _Float16* __restrict__ Krow,
                                        const float* v, int lane) {
    float sum = 0.0f;
#pragma unroll
    for (int s = 0; s < 4; ++s) {
        const int j = (s * 64 + lane) * 8;
        union { uint4 u; _Float16 h[8]; } kv;
        kv.u = *(const uint4*)(Krow + j);
        float4 c0 = *(const float4*)(v + j);
        float4 c1 = *(const float4*)(v + j + 4);
        sum += (float)kv.h[0] * c0.x + (float)kv.h[1] * c0.y +
               (float)kv.h[2] * c0.z + (float)kv.h[3] * c0.w +
               (float)kv.h[4] * c1.x + (float)kv.h[5] * c1.y +
               (float)kv.h[6] * c1.z + (float)kv.h[7] * c1.w;
    }
    if (lane == 0) sum += (float)Krow[2048] * v[2048];
#pragma unroll
    for (int off = 32; off; off >>= 1) sum += __shfl_xor(sum, off, 64);
    return sum;   // full sum in every lane
}

__global__ __launch_bounds__(TPB) void sinkhorn_persist(
    const _Float16* __restrict__ K0h, const _Float16* __restrict__ K0hT,
    float* r, float* c, unsigned* slots, unsigned* chg)
{
    const int wave = threadIdx.x >> 6, lane = threadIdx.x & 63;
    const int row = blockIdx.x * 8 + wave;
    const bool active = row < NA;
    const _Float16* KrowA = K0h  + (size_t)row * LDH;
    const _Float16* KrowB = K0hT + (size_t)row * LDH;
    __shared__ int ls_chg, ls_exit;
    float c_prev = 1.0f;   // lane 0 tracks previous c[row]

    for (int it = 0; it < ITERS; ++it) {
        if (threadIdx.x == 0) ls_chg = 0;
        // phase 1: r = 1 / (K0 c)
        if (active) {
            float s = rowdot(KrowA, c, lane);
            if (lane == 0) r[row] = 1.0f / s;
        }
        grid_barrier(&slots[2 * it]);           // also orders ls_chg reset
        // phase 2: c = 1 / (K0^T r)
        float cv = 0.0f;
        if (active) {
            float s = rowdot(KrowB, r, lane);
            cv = 1.0f / s;
            if (lane == 0) c[row] = cv;
        }
        if (active && lane == 0) {
            if (fabsf(cv - c_prev) > 1e-6f * fabsf(c_prev)) ls_chg = 1;  // benign race
            c_prev = cv;
        }
        __syncthreads();
        if (threadIdx.x == 0 && ls_chg)
            __hip_atomic_fetch_or(&chg[it], 1u, __ATOMIC_RELAXED,
                                  __HIP_MEMORY_SCOPE_AGENT);
        grid_barrier(&slots[2 * it + 1]);
        if (threadIdx.x == 0)
            ls_exit = (__hip_atomic_load(&chg[it], __ATOMIC_RELAXED,
                                         __HIP_MEMORY_SCOPE_AGENT) == 0u);
        __syncthreads();
        if (ls_exit) break;   // uniform across grid: all read the same flag
    }
}

// ---------------------------------------------------------------------------
// finalize: K = diag(r) K0 diag(c) in place (f32), P = K[:M,:N]
// ---------------------------------------------------------------------------
__global__ __launch_bounds__(256) void finalize(const float* __restrict__ r,
                                                const float* __restrict__ c,
                                                float* __restrict__ Kreg,
                                                float* __restrict__ P) {
    const int row = blockIdx.x;
    const float rs = r[row];
    for (int col = threadIdx.x; col < NA; col += 256) {
        float v = Kreg[(size_t)row * NA + col] * rs * c[col];
        Kreg[(size_t)row * NA + col] = v;
        if (row < MM && col < NN) P[(size_t)row * NN + col] = v;
    }
}

// ---------------------------------------------------------------------------
extern "C" void kernel_launch(void* const* d_in, const int* in_sizes, int n_in,
                              void* d_out, int out_size, void* d_ws, size_t ws_size,
                              hipStream_t stream) {
    const float* Q  = (const float*)d_in[0];
    const float* Rm = (const float*)d_in[1];
    const float* zp = (const float*)d_in[2];

    float* P    = (float*)d_out;
    float* Kreg = P + (size_t)MM * NN;       // f32 K0 / final K lives in d_out

    char* ws = (char*)d_ws;
    const size_t HBYTES = 8425728;           // NA*LDH*2 rounded to 256
    _Float16* K0h  = (_Float16*)ws;
    _Float16* K0hT = (_Float16*)(ws + HBYTES);
    float* c = (float*)(ws + 2 * HBYTES);
    float* r = c + 2560;
    unsigned* ctrl = (unsigned*)(r + 2560);  // [0..255]=barrier slots, [256..]=chg
    unsigned* slots = ctrl;
    unsigned* chg   = ctrl + 256;

    init_fill<<<dim3(9), dim3(256), 0, stream>>>(Kreg, K0h, c, ctrl, zp);
    gemm_exp<<<dim3(32, 32), dim3(256), 0, stream>>>(Q, Rm, Kreg, K0h);
    transpose_h<<<dim3(33, 33), dim3(256), 0, stream>>>(K0h, K0hT);
    sinkhorn_persist<<<dim3(NWG), dim3(TPB), 0, stream>>>(K0h, K0hT, r, c, slots, chg);
    finalize<<<dim3(2049), dim3(256), 0, stream>>>(r, c, Kreg, P);
}

// Round 3
// 120.027 us; speedup vs baseline: 5.8056x; 1.3853x over previous
//
#include <hip/hip_runtime.h>
#include <hip/hip_fp16.h>

#define MM 2048
#define NN 2048
#define DD 512
#define NA 2049        // augmented dim (m+1 = n+1)
#define LDH 2056       // fp16 padded row stride (4112 B, 16B-aligned)
#define LDE 1024       // split-bf16 row stride ([hi(512) | lo(512)])
#define ITERS 100
#define NWG 257        // persistent grid
#define TPB 512

typedef __attribute__((ext_vector_type(8))) short short8;
typedef __attribute__((ext_vector_type(4))) float f32x4;

__device__ __forceinline__ unsigned short f2bf(float x) {
    unsigned u = __builtin_bit_cast(unsigned, x);
    u += 0x7FFFu + ((u >> 16) & 1u);          // round-to-nearest-even
    return (unsigned short)(u >> 16);
}
__device__ __forceinline__ float bf2f(unsigned short h) {
    unsigned u = ((unsigned)h) << 16;
    return __builtin_bit_cast(float, u);
}
__device__ __forceinline__ void gload_lds16(const void* g, void* l) {
    __builtin_amdgcn_global_load_lds(
        (const __attribute__((address_space(1))) void*)g,
        (__attribute__((address_space(3))) void*)l, 16, 0, 0);
}

// ---------------------------------------------------------------------------
// init: c = 1, augmented row/col of K0, zero barrier/convergence control block
// ---------------------------------------------------------------------------
__global__ __launch_bounds__(256) void init_fill(float* __restrict__ Kreg,
                                                 _Float16* __restrict__ K0h,
                                                 float* __restrict__ c,
                                                 unsigned* __restrict__ ctrl,
                                                 const float* __restrict__ zp) {
    int t = blockIdx.x * 256 + threadIdx.x;
    float e5 = expf(zp[0] * 10.0f);   // exp(z/eps)
    if (t < 512) ctrl[t] = 0u;
    if (t < NA) {
        c[t] = 1.0f;
        Kreg[(size_t)2048 * NA + t] = e5;
        K0h[(size_t)2048 * LDH + t] = (_Float16)e5;
    }
    if (t < MM) {
        Kreg[(size_t)t * NA + 2048] = e5;
        K0h[(size_t)t * LDH + 2048] = (_Float16)e5;
    }
}

// ---------------------------------------------------------------------------
// split each f32 input into bf16 hi|lo, concatenated along K (row stride 1024)
// ---------------------------------------------------------------------------
__global__ __launch_bounds__(256) void split_bf16(const float* __restrict__ Q,
                                                  const float* __restrict__ Rm,
                                                  ushort* __restrict__ Qe,
                                                  ushort* __restrict__ Re) {
    const float* src = blockIdx.y ? Rm : Q;
    ushort* dst = blockIdx.y ? Re : Qe;
    int e4 = blockIdx.x * 256 + threadIdx.x;        // 0..262143 (float4 units)
    int row = e4 >> 7;                              // 128 float4 per 512-col row
    int c4 = (e4 & 127) * 4;
    float4 v = *(const float4*)(src + (size_t)row * DD + c4);
    ushort4 hi, lo;
    hi.x = f2bf(v.x); lo.x = f2bf(v.x - bf2f(hi.x));
    hi.y = f2bf(v.y); lo.y = f2bf(v.y - bf2f(hi.y));
    hi.z = f2bf(v.z); lo.z = f2bf(v.z - bf2f(hi.z));
    hi.w = f2bf(v.w); lo.w = f2bf(v.w - bf2f(hi.w));
    *(ushort4*)(dst + (size_t)row * LDE + c4) = hi;
    *(ushort4*)(dst + (size_t)row * LDE + 512 + c4) = lo;
}

// ---------------------------------------------------------------------------
// bf16 MFMA GEMM over K'=1024 (hi|lo concat) + exp epilogue
// 64x128 tile, 4 waves (2x2), each wave 32x64, BK=32, global_load_lds staging
// ---------------------------------------------------------------------------
__global__ __launch_bounds__(256, 2) void gemm_mfma(const ushort* __restrict__ Ae,
                                                    const ushort* __restrict__ Be,
                                                    float* __restrict__ Kreg,
                                                    _Float16* __restrict__ K0h) {
    __shared__ ushort Als[64 * 32];
    __shared__ ushort Bls[128 * 32];
    const int tid = threadIdx.x;
    const int wid = tid >> 6, lane = tid & 63;
    const int row0 = blockIdx.y * 64, col0 = blockIdx.x * 128;
    const int wr = wid >> 1, wc = wid & 1;

    // staging: wave w covers 16 consecutive rows; lane -> (row l>>2, 16B col (l&3))
    const int sr = lane >> 2, sc = (lane & 3) * 8;
    const ushort* gA  = Ae + (size_t)(row0 + wid * 16 + sr) * LDE + sc;
    const ushort* gB0 = Be + (size_t)(col0 + wid * 16 + sr) * LDE + sc;
    const ushort* gB1 = Be + (size_t)(col0 + 64 + wid * 16 + sr) * LDE + sc;
    ushort* lA  = &Als[wid * 16 * 32];          // wave-uniform LDS bases
    ushort* lB0 = &Bls[wid * 16 * 32];
    ushort* lB1 = &Bls[(64 + wid * 16) * 32];

    f32x4 acc[2][4] = {};
    const int fr = lane & 15, fk = (lane >> 4) * 8;

    for (int k0 = 0; k0 < 1024; k0 += 32) {
        __syncthreads();                        // prev compute done reading LDS
        gload_lds16(gA + k0, lA);
        gload_lds16(gB0 + k0, lB0);
        gload_lds16(gB1 + k0, lB1);
        __syncthreads();                        // compiler drains vmcnt here
        short8 a[2], b[4];
#pragma unroll
        for (int mi = 0; mi < 2; ++mi)
            a[mi] = *(const short8*)&Als[(wr * 32 + mi * 16 + fr) * 32 + fk];
#pragma unroll
        for (int ni = 0; ni < 4; ++ni)
            b[ni] = *(const short8*)&Bls[(wc * 64 + ni * 16 + fr) * 32 + fk];
#pragma unroll
        for (int mi = 0; mi < 2; ++mi)
#pragma unroll
            for (int ni = 0; ni < 4; ++ni)
                acc[mi][ni] = __builtin_amdgcn_mfma_f32_16x16x32_bf16(
                    a[mi], b[ni], acc[mi][ni], 0, 0, 0);
    }

#pragma unroll
    for (int mi = 0; mi < 2; ++mi)
#pragma unroll
        for (int ni = 0; ni < 4; ++ni)
#pragma unroll
            for (int q = 0; q < 4; ++q) {
                int row = row0 + wr * 32 + mi * 16 + (lane >> 4) * 4 + q;
                int col = col0 + wc * 64 + ni * 16 + fr;
                float v = expf(acc[mi][ni][q] * 10.0f);
                Kreg[(size_t)row * NA + col] = v;
                K0h[(size_t)row * LDH + col] = (_Float16)v;
            }
}

// ---------------------------------------------------------------------------
// fp16 transpose (full 2049x2049 incl augmented entries)
// ---------------------------------------------------------------------------
__global__ __launch_bounds__(256) void transpose_h(const _Float16* __restrict__ src,
                                                   _Float16* __restrict__ dst) {
    __shared__ _Float16 t[64][65];
    const int x0 = blockIdx.x * 64, y0 = blockIdx.y * 64;
    const int lx = threadIdx.x & 63, lyb = threadIdx.x >> 6;
    for (int ly = lyb; ly < 64; ly += 4) {
        int y = y0 + ly, x = x0 + lx;
        if (y < NA && x < NA) t[ly][lx] = src[(size_t)y * LDH + x];
    }
    __syncthreads();
    for (int ly = lyb; ly < 64; ly += 4) {
        int y = x0 + ly, x = y0 + lx;
        if (y < NA && x < NA) dst[(size_t)y * LDH + x] = t[lx][ly];
    }
}

// ---------------------------------------------------------------------------
// persistent Sinkhorn loop: slotted grid barrier, one row per wave
// ---------------------------------------------------------------------------
__device__ __forceinline__ void grid_barrier(unsigned* slot) {
    __syncthreads();
    if (threadIdx.x == 0) {
        __hip_atomic_fetch_add(slot, 1u, __ATOMIC_ACQ_REL, __HIP_MEMORY_SCOPE_AGENT);
        while (__hip_atomic_load(slot, __ATOMIC_ACQUIRE, __HIP_MEMORY_SCOPE_AGENT)
               != (unsigned)NWG)
            __builtin_amdgcn_s_sleep(1);
    }
    __syncthreads();
}

__device__ __forceinline__ float rowdot(const _Float16* __restrict__ Krow,
                                        const float* v, int lane) {
    float sum = 0.0f;
#pragma unroll
    for (int s = 0; s < 4; ++s) {
        const int j = (s * 64 + lane) * 8;
        union { uint4 u; _Float16 h[8]; } kv;
        kv.u = *(const uint4*)(Krow + j);
        float4 c0 = *(const float4*)(v + j);
        float4 c1 = *(const float4*)(v + j + 4);
        sum += (float)kv.h[0] * c0.x + (float)kv.h[1] * c0.y +
               (float)kv.h[2] * c0.z + (float)kv.h[3] * c0.w +
               (float)kv.h[4] * c1.x + (float)kv.h[5] * c1.y +
               (float)kv.h[6] * c1.z + (float)kv.h[7] * c1.w;
    }
    if (lane == 0) sum += (float)Krow[2048] * v[2048];
#pragma unroll
    for (int off = 32; off; off >>= 1) sum += __shfl_xor(sum, off, 64);
    return sum;
}

__global__ __launch_bounds__(TPB) void sinkhorn_persist(
    const _Float16* __restrict__ K0h, const _Float16* __restrict__ K0hT,
    float* r, float* c, unsigned* slots, unsigned* chg)
{
    const int wave = threadIdx.x >> 6, lane = threadIdx.x & 63;
    const int row = blockIdx.x * 8 + wave;
    const bool active = row < NA;
    const _Float16* KrowA = K0h  + (size_t)row * LDH;
    const _Float16* KrowB = K0hT + (size_t)row * LDH;
    __shared__ int ls_chg, ls_exit;
    float c_prev = 1.0f;

    for (int it = 0; it < ITERS; ++it) {
        if (threadIdx.x == 0) ls_chg = 0;
        if (active) {
            float s = rowdot(KrowA, c, lane);
            if (lane == 0) r[row] = 1.0f / s;
        }
        grid_barrier(&slots[2 * it]);
        float cv = 0.0f;
        if (active) {
            float s = rowdot(KrowB, r, lane);
            cv = 1.0f / s;
            if (lane == 0) c[row] = cv;
        }
        if (active && lane == 0) {
            if (fabsf(cv - c_prev) > 1e-6f * fabsf(c_prev)) ls_chg = 1;
            c_prev = cv;
        }
        __syncthreads();
        if (threadIdx.x == 0 && ls_chg)
            __hip_atomic_fetch_or(&chg[it], 1u, __ATOMIC_RELAXED,
                                  __HIP_MEMORY_SCOPE_AGENT);
        grid_barrier(&slots[2 * it + 1]);
        if (threadIdx.x == 0)
            ls_exit = (__hip_atomic_load(&chg[it], __ATOMIC_RELAXED,
                                         __HIP_MEMORY_SCOPE_AGENT) == 0u);
        __syncthreads();
        if (ls_exit) break;
    }
}

// ---------------------------------------------------------------------------
// finalize: K = diag(r) K0 diag(c) in place (f32), P = K[:M,:N]
// ---------------------------------------------------------------------------
__global__ __launch_bounds__(256) void finalize(const float* __restrict__ r,
                                                const float* __restrict__ c,
                                                float* __restrict__ Kreg,
                                                float* __restrict__ P) {
    const int row = blockIdx.x;
    const float rs = r[row];
    for (int col = threadIdx.x; col < NA; col += 256) {
        float v = Kreg[(size_t)row * NA + col] * rs * c[col];
        Kreg[(size_t)row * NA + col] = v;
        if (row < MM && col < NN) P[(size_t)row * NN + col] = v;
    }
}

// ---------------------------------------------------------------------------
extern "C" void kernel_launch(void* const* d_in, const int* in_sizes, int n_in,
                              void* d_out, int out_size, void* d_ws, size_t ws_size,
                              hipStream_t stream) {
    const float* Q  = (const float*)d_in[0];
    const float* Rm = (const float*)d_in[1];
    const float* zp = (const float*)d_in[2];

    float* P    = (float*)d_out;
    float* Kreg = P + (size_t)MM * NN;

    // stage split-bf16 inputs in the P region (P only written by finalize, last)
    ushort* Qe = (ushort*)d_out;                 // 4 MB
    ushort* Re = Qe + (size_t)2048 * LDE;        // 4 MB

    char* ws = (char*)d_ws;
    const size_t HBYTES = 8425728;               // NA*LDH*2 rounded to 256
    _Float16* K0h  = (_Float16*)ws;
    _Float16* K0hT = (_Float16*)(ws + HBYTES);
    float* c = (float*)(ws + 2 * HBYTES);
    float* r = c + 2560;
    unsigned* ctrl = (unsigned*)(r + 2560);
    unsigned* slots = ctrl;
    unsigned* chg   = ctrl + 256;

    init_fill<<<dim3(9), dim3(256), 0, stream>>>(Kreg, K0h, c, ctrl, zp);
    split_bf16<<<dim3(1024, 2), dim3(256), 0, stream>>>(Q, Rm, Qe, Re);
    gemm_mfma<<<dim3(16, 32), dim3(256), 0, stream>>>(Qe, Re, Kreg, K0h);
    transpose_h<<<dim3(33, 33), dim3(256), 0, stream>>>(K0h, K0hT);
    sinkhorn_persist<<<dim3(NWG), dim3(TPB), 0, stream>>>(K0h, K0hT, r, c, slots, chg);
    finalize<<<dim3(2049), dim3(256), 0, stream>>>(r, c, Kreg, P);
}